// Round 6
// baseline (81.501 us; speedup 1.0000x reference)
//
#include <hip/hip_runtime.h>

#define D        128
#define NT       256
#define CAP      64       // per-dst bucket capacity (avg degree 12.8, max ~34)
#define OVF_CAP  65536    // overflow list capacity (unused for this input)

typedef __attribute__((ext_vector_type(4))) _Float16 half4;

__device__ __forceinline__ float4 elu_mul(float4 g, float4 w) {
    float4 v;
    v.x = g.x * w.x; v.y = g.y * w.y; v.z = g.z * w.z; v.w = g.w * w.w;
    v.x = (v.x > 0.0f) ? v.x : (__expf(v.x) - 1.0f);
    v.y = (v.y > 0.0f) ? v.y : (__expf(v.y) - 1.0f);
    v.z = (v.z > 0.0f) ? v.z : (__expf(v.z) - 1.0f);
    v.w = (v.w > 0.0f) ? v.w : (__expf(v.w) - 1.0f);
    return v;
}

__device__ __forceinline__ void put_edge(int d, int s, int ef,
                                         int* __restrict__ counts,
                                         unsigned int* __restrict__ bucket,
                                         int* __restrict__ ovf_cnt,
                                         int* __restrict__ ovf) {
    unsigned int flag = (ef == 0 || ef == 6 || ef == 14 || ef == 30) ? 1u : 0u;
    unsigned int rec  = (unsigned int)s | (flag << 31);
    int pos = atomicAdd(&counts[d], 1);
    if (pos < CAP) {
        bucket[((size_t)d << 6) + pos] = rec;
    } else {
        int op = atomicAdd(ovf_cnt, 1);
        if (op < OVF_CAP) { ovf[2 * op] = d; ovf[2 * op + 1] = (int)rec; }
    }
}

// ---------------------------------------------------------------------------
// Fused pre-pass. Blocks [0, eb): edge bucketing, 4 edges/thread, one pass,
// int4 loads -> 4 independent atomic->store chains (ILP hides L2 latency).
// Blocks [eb, grid): emb = elu(ge*w) in fp16, grid-stride.
// ---------------------------------------------------------------------------
__global__ __launch_bounds__(NT)
void fused_pre_kernel(const float* __restrict__ ge, const float* __restrict__ weight,
                      const int* __restrict__ e_feat, const int* __restrict__ src,
                      const int* __restrict__ dst,
                      _Float16* __restrict__ emb, int* __restrict__ counts,
                      unsigned int* __restrict__ bucket,
                      int* __restrict__ ovf_cnt, int* __restrict__ ovf,
                      int n_nodes, int n_edges, int eb) {
    if ((int)blockIdx.x < eb) {
        int t = blockIdx.x * NT + threadIdx.x;
        int base = t * 4;
        if (base + 4 <= n_edges) {
            int4 d4 = *reinterpret_cast<const int4*>(dst + base);
            int4 s4 = *reinterpret_cast<const int4*>(src + base);
            int4 f4 = *reinterpret_cast<const int4*>(e_feat + base);
            put_edge(d4.x, s4.x, f4.x, counts, bucket, ovf_cnt, ovf);
            put_edge(d4.y, s4.y, f4.y, counts, bucket, ovf_cnt, ovf);
            put_edge(d4.z, s4.z, f4.z, counts, bucket, ovf_cnt, ovf);
            put_edge(d4.w, s4.w, f4.w, counts, bucket, ovf_cnt, ovf);
        } else if (base < n_edges) {
            for (int e = base; e < n_edges; ++e)
                put_edge(dst[e], src[e], e_feat[e], counts, bucket, ovf_cnt, ovf);
        }
    } else {
        int tid = (blockIdx.x - eb) * NT + threadIdx.x;
        int nthr = (gridDim.x - eb) * NT;
        int quads = n_nodes * (D / 4);
        for (int q = tid; q < quads; q += nthr) {
            int col = (q & 31) * 4;  // 32 quads per row
            float4 g = *reinterpret_cast<const float4*>(ge + (size_t)q * 4);
            float4 w = *reinterpret_cast<const float4*>(weight + col);
            float4 v = elu_mul(g, w);
            half4 h;
            h.x = (_Float16)v.x; h.y = (_Float16)v.y;
            h.z = (_Float16)v.z; h.w = (_Float16)v.w;
            *reinterpret_cast<half4*>(emb + (size_t)q * 4) = h;
        }
    }
}

// ---------------------------------------------------------------------------
// Gather: 32 lanes/node, 4 fp16 cols/lane, uint4 record loads (4 edges/load).
// ---------------------------------------------------------------------------
__global__ __launch_bounds__(NT)
void gather_kernel(const _Float16* __restrict__ emb,
                   const int* __restrict__ counts,
                   const unsigned int* __restrict__ bucket,
                   const int* __restrict__ ovf_cnt, const int* __restrict__ ovf,
                   float* __restrict__ out, int n_nodes) {
    int tid = blockIdx.x * NT + threadIdx.x;
    int node = tid >> 5;
    if (node >= n_nodes) return;
    int col = (tid & 31) * 4;

    float4 acc = make_float4(0.f, 0.f, 0.f, 0.f);
    int cnt = counts[node];
    if (cnt > CAP) cnt = CAP;
    const unsigned int* bkt = bucket + ((size_t)node << 6);

    int i = 0;
    for (; i + 4 <= cnt; i += 4) {
        uint4 r = *reinterpret_cast<const uint4*>(bkt + i);  // broadcast 16 B
        half4 h0 = *reinterpret_cast<const half4*>(emb + (size_t)(r.x & 0x7FFFFFFFu) * D + col);
        half4 h1 = *reinterpret_cast<const half4*>(emb + (size_t)(r.y & 0x7FFFFFFFu) * D + col);
        half4 h2 = *reinterpret_cast<const half4*>(emb + (size_t)(r.z & 0x7FFFFFFFu) * D + col);
        half4 h3 = *reinterpret_cast<const half4*>(emb + (size_t)(r.w & 0x7FFFFFFFu) * D + col);
        float m0 = (r.x >> 31) ? 2.0f : 1.0f;
        float m1 = (r.y >> 31) ? 2.0f : 1.0f;
        float m2 = (r.z >> 31) ? 2.0f : 1.0f;
        float m3 = (r.w >> 31) ? 2.0f : 1.0f;
        acc.x += (float)h0.x * m0; acc.y += (float)h0.y * m0;
        acc.z += (float)h0.z * m0; acc.w += (float)h0.w * m0;
        acc.x += (float)h1.x * m1; acc.y += (float)h1.y * m1;
        acc.z += (float)h1.z * m1; acc.w += (float)h1.w * m1;
        acc.x += (float)h2.x * m2; acc.y += (float)h2.y * m2;
        acc.z += (float)h2.z * m2; acc.w += (float)h2.w * m2;
        acc.x += (float)h3.x * m3; acc.y += (float)h3.y * m3;
        acc.z += (float)h3.z * m3; acc.w += (float)h3.w * m3;
    }
    for (; i < cnt; ++i) {
        unsigned int r = bkt[i];
        half4 h = *reinterpret_cast<const half4*>(emb + (size_t)(r & 0x7FFFFFFFu) * D + col);
        float m = (r >> 31) ? 2.0f : 1.0f;
        acc.x += (float)h.x * m; acc.y += (float)h.y * m;
        acc.z += (float)h.z * m; acc.w += (float)h.w * m;
    }

    // Overflow guard (expected empty)
    int no = *ovf_cnt;
    if (no > 0) {
        if (no > OVF_CAP) no = OVF_CAP;
        for (int k = 0; k < no; ++k) {
            if (ovf[2 * k] == node) {
                unsigned int r = (unsigned int)ovf[2 * k + 1];
                half4 h = *reinterpret_cast<const half4*>(emb + (size_t)(r & 0x7FFFFFFFu) * D + col);
                float m = (r >> 31) ? 2.0f : 1.0f;
                acc.x += (float)h.x * m; acc.y += (float)h.y * m;
                acc.z += (float)h.z * m; acc.w += (float)h.w * m;
            }
        }
    }

    *reinterpret_cast<float4*>(out + (size_t)node * D + col) = acc;
}

// ---------------------------------------------------------------------------
// Fallback (tiny workspace): atomic scatter.
// ---------------------------------------------------------------------------
__global__ void edge_scatter_fallback(const float* __restrict__ ge,
                                      const float* __restrict__ weight,
                                      const int* __restrict__ e_feat,
                                      const int* __restrict__ src,
                                      const int* __restrict__ dst,
                                      float* __restrict__ out, int n_edges) {
    long long tid = (long long)blockIdx.x * blockDim.x + threadIdx.x;
    int edge = (int)(tid >> 5);
    if (edge >= n_edges) return;
    int col = (int)(tid & 31) * 4;
    int e = e_feat[edge];
    float mult = (e == 0 || e == 6 || e == 14 || e == 30) ? 2.0f : 1.0f;
    float4 w = *reinterpret_cast<const float4*>(weight + col);
    float4 g = *reinterpret_cast<const float4*>(ge + (long long)src[edge] * D + col);
    float4 v = elu_mul(g, w);
    float* o = out + (long long)dst[edge] * D + col;
    atomicAdd(o + 0, v.x * mult);
    atomicAdd(o + 1, v.y * mult);
    atomicAdd(o + 2, v.z * mult);
    atomicAdd(o + 3, v.w * mult);
}

extern "C" void kernel_launch(void* const* d_in, const int* in_sizes, int n_in,
                              void* d_out, int out_size, void* d_ws, size_t ws_size,
                              hipStream_t stream) {
    const float* ge     = (const float*)d_in[0];   // [N, 128]
    const float* weight = (const float*)d_in[1];   // [1, 128]
    const int*   e_feat = (const int*)d_in[2];     // [E]
    const int*   src    = (const int*)d_in[3];     // [E]
    const int*   dst    = (const int*)d_in[4];     // [E]
    float* out = (float*)d_out;                    // [N, 128]

    int n_edges = in_sizes[2];
    int n_nodes = out_size / D;

    // Workspace: emb | counts | ovf_cnt | bucket | ovf
    auto align256 = [](size_t x) { return (x + 255) & ~(size_t)255; };
    size_t o_emb    = 0;
    size_t o_counts = o_emb    + align256((size_t)n_nodes * D * sizeof(_Float16));
    size_t o_ovfcnt = o_counts + align256((size_t)n_nodes * 4);
    size_t o_bucket = o_ovfcnt + 256;
    size_t o_ovf    = o_bucket + align256((size_t)n_nodes * CAP * 4);
    size_t need     = o_ovf + (size_t)OVF_CAP * 8 + 256;

    if (ws_size < need) {
        hipMemsetAsync(d_out, 0, (size_t)out_size * sizeof(float), stream);
        long long total = (long long)n_edges * 32;
        edge_scatter_fallback<<<(int)((total + 255) / 256), 256, 0, stream>>>(
            ge, weight, e_feat, src, dst, out, n_edges);
        return;
    }

    char* ws = (char*)d_ws;
    _Float16*     emb     = (_Float16*)(ws + o_emb);
    int*          counts  = (int*)(ws + o_counts);
    int*          ovf_cnt = (int*)(ws + o_ovfcnt);
    unsigned int* bucket  = (unsigned int*)(ws + o_bucket);
    int*          ovf     = (int*)(ws + o_ovf);

    // One memset covers counts + ovf_cnt (contiguous).
    hipMemsetAsync(counts, 0, (o_bucket - o_counts), stream);

    // Edge partition: one pass, 4 edges/thread.
    int eb = (n_edges + 4 * NT - 1) / (4 * NT);   // 625 for E=640000
    int GRID = eb + 1423;                          // emb partition gets the rest
    fused_pre_kernel<<<GRID, NT, 0, stream>>>(ge, weight, e_feat, src, dst,
                                              emb, counts, bucket, ovf_cnt, ovf,
                                              n_nodes, n_edges, eb);

    long long total = (long long)n_nodes * 32;
    gather_kernel<<<(int)((total + 255) / 256), NT, 0, stream>>>(
        emb, counts, bucket, ovf_cnt, ovf, out, n_nodes);
}

// Round 7
// 76.047 us; speedup vs baseline: 1.0717x; 1.0717x over previous
//
#include <hip/hip_runtime.h>

#define D        128
#define NT       256
#define CAP      64       // per-dst bucket capacity (avg degree 12.8, max ~35)
#define OVF_CAP  65536    // overflow list capacity (unused for this input)

typedef __attribute__((ext_vector_type(4))) _Float16 half4;

__device__ __forceinline__ float4 elu_mul(float4 g, float4 w) {
    float4 v;
    v.x = g.x * w.x; v.y = g.y * w.y; v.z = g.z * w.z; v.w = g.w * w.w;
    v.x = (v.x > 0.0f) ? v.x : (__expf(v.x) - 1.0f);
    v.y = (v.y > 0.0f) ? v.y : (__expf(v.y) - 1.0f);
    v.z = (v.z > 0.0f) ? v.z : (__expf(v.z) - 1.0f);
    v.w = (v.w > 0.0f) ? v.w : (__expf(v.w) - 1.0f);
    return v;
}

// ---------------------------------------------------------------------------
// Fused pre-pass, latency-hiding order:
//   phase 1: issue ALL edge atomics (<=2/thread, no dependent use)  -- in flight
//   phase 2: emb = elu(ge*w) fp16 (independent memory work, hides phase-1 lat)
//   phase 3: consume returned slots, scatter bucket stores
// ---------------------------------------------------------------------------
__global__ __launch_bounds__(NT)
void fused_pre_kernel(const float* __restrict__ ge, const float* __restrict__ weight,
                      const int* __restrict__ e_feat, const int* __restrict__ src,
                      const int* __restrict__ dst,
                      _Float16* __restrict__ emb, int* __restrict__ counts,
                      unsigned int* __restrict__ bucket,
                      int* __restrict__ ovf_cnt, int* __restrict__ ovf,
                      int n_nodes, int n_edges) {
    const int t = blockIdx.x * NT + threadIdx.x;
    const int T = gridDim.x * NT;

    // --- phase 1: edge loads + atomics, nothing consumes pos yet ---------
    int e0 = t, e1 = t + T;
    bool v0 = (e0 < n_edges), v1 = (e1 < n_edges);
    int d0 = 0, d1 = 0, pos0 = 0, pos1 = 0;
    unsigned int rec0 = 0, rec1 = 0;
    if (v0) {
        d0 = dst[e0];
        int f0 = e_feat[e0];
        unsigned int flag0 = (f0 == 0 || f0 == 6 || f0 == 14 || f0 == 30) ? 1u : 0u;
        rec0 = (unsigned int)src[e0] | (flag0 << 31);
        pos0 = atomicAdd(&counts[d0], 1);
    }
    if (v1) {
        d1 = dst[e1];
        int f1 = e_feat[e1];
        unsigned int flag1 = (f1 == 0 || f1 == 6 || f1 == 14 || f1 == 30) ? 1u : 0u;
        rec1 = (unsigned int)src[e1] | (flag1 << 31);
        pos1 = atomicAdd(&counts[d1], 1);
    }

    // --- phase 2: emb build (independent; covers atomic round-trips) -----
    int quads = n_nodes * (D / 4);
    for (int q = t; q < quads; q += T) {
        int col = (q & 31) * 4;  // 32 quads per row
        float4 g = *reinterpret_cast<const float4*>(ge + (size_t)q * 4);
        float4 w = *reinterpret_cast<const float4*>(weight + col);
        float4 v = elu_mul(g, w);
        half4 h;
        h.x = (_Float16)v.x; h.y = (_Float16)v.y;
        h.z = (_Float16)v.z; h.w = (_Float16)v.w;
        *reinterpret_cast<half4*>(emb + (size_t)q * 4) = h;
    }

    // --- phase 3: bucket stores (atomic results long since landed) -------
    if (v0) {
        if (pos0 < CAP) {
            bucket[((size_t)d0 << 6) + pos0] = rec0;
        } else {
            int op = atomicAdd(ovf_cnt, 1);
            if (op < OVF_CAP) { ovf[2 * op] = d0; ovf[2 * op + 1] = (int)rec0; }
        }
    }
    if (v1) {
        if (pos1 < CAP) {
            bucket[((size_t)d1 << 6) + pos1] = rec1;
        } else {
            int op = atomicAdd(ovf_cnt, 1);
            if (op < OVF_CAP) { ovf[2 * op] = d1; ovf[2 * op + 1] = (int)rec1; }
        }
    }
}

// ---------------------------------------------------------------------------
// Gather: 32 lanes/node, 4 fp16 cols/lane, uint4 record loads (4 edges/load).
// ---------------------------------------------------------------------------
__global__ __launch_bounds__(NT)
void gather_kernel(const _Float16* __restrict__ emb,
                   const int* __restrict__ counts,
                   const unsigned int* __restrict__ bucket,
                   const int* __restrict__ ovf_cnt, const int* __restrict__ ovf,
                   float* __restrict__ out, int n_nodes) {
    int tid = blockIdx.x * NT + threadIdx.x;
    int node = tid >> 5;
    if (node >= n_nodes) return;
    int col = (tid & 31) * 4;

    float4 acc = make_float4(0.f, 0.f, 0.f, 0.f);
    int cnt = counts[node];
    if (cnt > CAP) cnt = CAP;
    const unsigned int* bkt = bucket + ((size_t)node << 6);

    int i = 0;
    for (; i + 4 <= cnt; i += 4) {
        uint4 r = *reinterpret_cast<const uint4*>(bkt + i);  // broadcast 16 B
        half4 h0 = *reinterpret_cast<const half4*>(emb + (size_t)(r.x & 0x7FFFFFFFu) * D + col);
        half4 h1 = *reinterpret_cast<const half4*>(emb + (size_t)(r.y & 0x7FFFFFFFu) * D + col);
        half4 h2 = *reinterpret_cast<const half4*>(emb + (size_t)(r.z & 0x7FFFFFFFu) * D + col);
        half4 h3 = *reinterpret_cast<const half4*>(emb + (size_t)(r.w & 0x7FFFFFFFu) * D + col);
        float m0 = (r.x >> 31) ? 2.0f : 1.0f;
        float m1 = (r.y >> 31) ? 2.0f : 1.0f;
        float m2 = (r.z >> 31) ? 2.0f : 1.0f;
        float m3 = (r.w >> 31) ? 2.0f : 1.0f;
        acc.x += (float)h0.x * m0; acc.y += (float)h0.y * m0;
        acc.z += (float)h0.z * m0; acc.w += (float)h0.w * m0;
        acc.x += (float)h1.x * m1; acc.y += (float)h1.y * m1;
        acc.z += (float)h1.z * m1; acc.w += (float)h1.w * m1;
        acc.x += (float)h2.x * m2; acc.y += (float)h2.y * m2;
        acc.z += (float)h2.z * m2; acc.w += (float)h2.w * m2;
        acc.x += (float)h3.x * m3; acc.y += (float)h3.y * m3;
        acc.z += (float)h3.z * m3; acc.w += (float)h3.w * m3;
    }
    for (; i < cnt; ++i) {
        unsigned int r = bkt[i];
        half4 h = *reinterpret_cast<const half4*>(emb + (size_t)(r & 0x7FFFFFFFu) * D + col);
        float m = (r >> 31) ? 2.0f : 1.0f;
        acc.x += (float)h.x * m; acc.y += (float)h.y * m;
        acc.z += (float)h.z * m; acc.w += (float)h.w * m;
    }

    // Overflow guard (expected empty)
    int no = *ovf_cnt;
    if (no > 0) {
        if (no > OVF_CAP) no = OVF_CAP;
        for (int k = 0; k < no; ++k) {
            if (ovf[2 * k] == node) {
                unsigned int r = (unsigned int)ovf[2 * k + 1];
                half4 h = *reinterpret_cast<const half4*>(emb + (size_t)(r & 0x7FFFFFFFu) * D + col);
                float m = (r >> 31) ? 2.0f : 1.0f;
                acc.x += (float)h.x * m; acc.y += (float)h.y * m;
                acc.z += (float)h.z * m; acc.w += (float)h.w * m;
            }
        }
    }

    *reinterpret_cast<float4*>(out + (size_t)node * D + col) = acc;
}

// ---------------------------------------------------------------------------
// Fallback (tiny workspace): atomic scatter.
// ---------------------------------------------------------------------------
__global__ void edge_scatter_fallback(const float* __restrict__ ge,
                                      const float* __restrict__ weight,
                                      const int* __restrict__ e_feat,
                                      const int* __restrict__ src,
                                      const int* __restrict__ dst,
                                      float* __restrict__ out, int n_edges) {
    long long tid = (long long)blockIdx.x * blockDim.x + threadIdx.x;
    int edge = (int)(tid >> 5);
    if (edge >= n_edges) return;
    int col = (int)(tid & 31) * 4;
    int e = e_feat[edge];
    float mult = (e == 0 || e == 6 || e == 14 || e == 30) ? 2.0f : 1.0f;
    float4 w = *reinterpret_cast<const float4*>(weight + col);
    float4 g = *reinterpret_cast<const float4*>(ge + (long long)src[edge] * D + col);
    float4 v = elu_mul(g, w);
    float* o = out + (long long)dst[edge] * D + col;
    atomicAdd(o + 0, v.x * mult);
    atomicAdd(o + 1, v.y * mult);
    atomicAdd(o + 2, v.z * mult);
    atomicAdd(o + 3, v.w * mult);
}

extern "C" void kernel_launch(void* const* d_in, const int* in_sizes, int n_in,
                              void* d_out, int out_size, void* d_ws, size_t ws_size,
                              hipStream_t stream) {
    const float* ge     = (const float*)d_in[0];   // [N, 128]
    const float* weight = (const float*)d_in[1];   // [1, 128]
    const int*   e_feat = (const int*)d_in[2];     // [E]
    const int*   src    = (const int*)d_in[3];     // [E]
    const int*   dst    = (const int*)d_in[4];     // [E]
    float* out = (float*)d_out;                    // [N, 128]

    int n_edges = in_sizes[2];
    int n_nodes = out_size / D;

    // Workspace: emb | counts | ovf_cnt | bucket | ovf
    auto align256 = [](size_t x) { return (x + 255) & ~(size_t)255; };
    size_t o_emb    = 0;
    size_t o_counts = o_emb    + align256((size_t)n_nodes * D * sizeof(_Float16));
    size_t o_ovfcnt = o_counts + align256((size_t)n_nodes * 4);
    size_t o_bucket = o_ovfcnt + 256;
    size_t o_ovf    = o_bucket + align256((size_t)n_nodes * CAP * 4);
    size_t need     = o_ovf + (size_t)OVF_CAP * 8 + 256;

    // Require <=2 edges per thread for the issue-early pattern.
    const int GRID = 2048;
    bool fits = ((long long)n_edges <= 2LL * GRID * NT);

    if (ws_size < need || !fits) {
        hipMemsetAsync(d_out, 0, (size_t)out_size * sizeof(float), stream);
        long long total = (long long)n_edges * 32;
        edge_scatter_fallback<<<(int)((total + 255) / 256), 256, 0, stream>>>(
            ge, weight, e_feat, src, dst, out, n_edges);
        return;
    }

    char* ws = (char*)d_ws;
    _Float16*     emb     = (_Float16*)(ws + o_emb);
    int*          counts  = (int*)(ws + o_counts);
    int*          ovf_cnt = (int*)(ws + o_ovfcnt);
    unsigned int* bucket  = (unsigned int*)(ws + o_bucket);
    int*          ovf     = (int*)(ws + o_ovf);

    // One memset covers counts + ovf_cnt (contiguous).
    hipMemsetAsync(counts, 0, (o_bucket - o_counts), stream);

    fused_pre_kernel<<<GRID, NT, 0, stream>>>(ge, weight, e_feat, src, dst,
                                              emb, counts, bucket, ovf_cnt, ovf,
                                              n_nodes, n_edges);

    long long total = (long long)n_nodes * 32;
    gather_kernel<<<(int)((total + 255) / 256), NT, 0, stream>>>(
        emb, counts, bucket, ovf_cnt, ovf, out, n_nodes);
}

// Round 8
// 72.405 us; speedup vs baseline: 1.1256x; 1.0503x over previous
//
#include <hip/hip_runtime.h>

#define D        128
#define NT       256
#define CAP      64       // per-dst bucket capacity (avg degree 12.8, max ~35)
#define CSH      4        // counts stride shift: 16 ints = one 64-B line per node
#define OVF_CAP  65536    // overflow list capacity (unused for this input)

typedef __attribute__((ext_vector_type(4))) _Float16 half4;

__device__ __forceinline__ float4 elu_mul(float4 g, float4 w) {
    float4 v;
    v.x = g.x * w.x; v.y = g.y * w.y; v.z = g.z * w.z; v.w = g.w * w.w;
    v.x = (v.x > 0.0f) ? v.x : (__expf(v.x) - 1.0f);
    v.y = (v.y > 0.0f) ? v.y : (__expf(v.y) - 1.0f);
    v.z = (v.z > 0.0f) ? v.z : (__expf(v.z) - 1.0f);
    v.w = (v.w > 0.0f) ? v.w : (__expf(v.w) - 1.0f);
    return v;
}

// ---------------------------------------------------------------------------
// Fused pre-pass (issue-early):
//   phase 1: issue all edge atomics (<=2/thread) -- padded counts, 1 ctr/line
//   phase 2: emb = elu(ge*w) fp16 (independent work hides atomic latency)
//   phase 3: consume slots, scatter bucket stores
// ---------------------------------------------------------------------------
__global__ __launch_bounds__(NT)
void fused_pre_kernel(const float* __restrict__ ge, const float* __restrict__ weight,
                      const int* __restrict__ e_feat, const int* __restrict__ src,
                      const int* __restrict__ dst,
                      _Float16* __restrict__ emb, int* __restrict__ counts,
                      unsigned int* __restrict__ bucket,
                      int* __restrict__ ovf_cnt, int* __restrict__ ovf,
                      int n_nodes, int n_edges) {
    const int t = blockIdx.x * NT + threadIdx.x;
    const int T = gridDim.x * NT;

    // --- phase 1: edge loads + atomics, nothing consumes pos yet ---------
    int e0 = t, e1 = t + T;
    bool v0 = (e0 < n_edges), v1 = (e1 < n_edges);
    int d0 = 0, d1 = 0, pos0 = 0, pos1 = 0;
    unsigned int rec0 = 0, rec1 = 0;
    if (v0) {
        d0 = dst[e0];
        int f0 = e_feat[e0];
        unsigned int flag0 = (f0 == 0 || f0 == 6 || f0 == 14 || f0 == 30) ? 1u : 0u;
        rec0 = (unsigned int)src[e0] | (flag0 << 31);
        pos0 = atomicAdd(&counts[d0 << CSH], 1);
    }
    if (v1) {
        d1 = dst[e1];
        int f1 = e_feat[e1];
        unsigned int flag1 = (f1 == 0 || f1 == 6 || f1 == 14 || f1 == 30) ? 1u : 0u;
        rec1 = (unsigned int)src[e1] | (flag1 << 31);
        pos1 = atomicAdd(&counts[d1 << CSH], 1);
    }

    // --- phase 2: emb build (independent; covers atomic round-trips) -----
    int quads = n_nodes * (D / 4);
    for (int q = t; q < quads; q += T) {
        int col = (q & 31) * 4;  // 32 quads per row
        float4 g = *reinterpret_cast<const float4*>(ge + (size_t)q * 4);
        float4 w = *reinterpret_cast<const float4*>(weight + col);
        float4 v = elu_mul(g, w);
        half4 h;
        h.x = (_Float16)v.x; h.y = (_Float16)v.y;
        h.z = (_Float16)v.z; h.w = (_Float16)v.w;
        *reinterpret_cast<half4*>(emb + (size_t)q * 4) = h;
    }

    // --- phase 3: bucket stores --------------------------------------------
    if (v0) {
        if (pos0 < CAP) {
            bucket[((size_t)d0 << 6) + pos0] = rec0;
        } else {
            int op = atomicAdd(ovf_cnt, 1);
            if (op < OVF_CAP) { ovf[2 * op] = d0; ovf[2 * op + 1] = (int)rec0; }
        }
    }
    if (v1) {
        if (pos1 < CAP) {
            bucket[((size_t)d1 << 6) + pos1] = rec1;
        } else {
            int op = atomicAdd(ovf_cnt, 1);
            if (op < OVF_CAP) { ovf[2 * op] = d1; ovf[2 * op + 1] = (int)rec1; }
        }
    }
}

// ---------------------------------------------------------------------------
// Gather: 32 lanes/node, 4 fp16 cols/lane, uint4 record loads (4 edges/load).
// ---------------------------------------------------------------------------
__global__ __launch_bounds__(NT)
void gather_kernel(const _Float16* __restrict__ emb,
                   const int* __restrict__ counts,
                   const unsigned int* __restrict__ bucket,
                   const int* __restrict__ ovf_cnt, const int* __restrict__ ovf,
                   float* __restrict__ out, int n_nodes) {
    int tid = blockIdx.x * NT + threadIdx.x;
    int node = tid >> 5;
    if (node >= n_nodes) return;
    int col = (tid & 31) * 4;

    float4 acc = make_float4(0.f, 0.f, 0.f, 0.f);
    int cnt = counts[node << CSH];
    if (cnt > CAP) cnt = CAP;
    const unsigned int* bkt = bucket + ((size_t)node << 6);

    int i = 0;
    for (; i + 4 <= cnt; i += 4) {
        uint4 r = *reinterpret_cast<const uint4*>(bkt + i);  // broadcast 16 B
        half4 h0 = *reinterpret_cast<const half4*>(emb + (size_t)(r.x & 0x7FFFFFFFu) * D + col);
        half4 h1 = *reinterpret_cast<const half4*>(emb + (size_t)(r.y & 0x7FFFFFFFu) * D + col);
        half4 h2 = *reinterpret_cast<const half4*>(emb + (size_t)(r.z & 0x7FFFFFFFu) * D + col);
        half4 h3 = *reinterpret_cast<const half4*>(emb + (size_t)(r.w & 0x7FFFFFFFu) * D + col);
        float m0 = (r.x >> 31) ? 2.0f : 1.0f;
        float m1 = (r.y >> 31) ? 2.0f : 1.0f;
        float m2 = (r.z >> 31) ? 2.0f : 1.0f;
        float m3 = (r.w >> 31) ? 2.0f : 1.0f;
        acc.x += (float)h0.x * m0; acc.y += (float)h0.y * m0;
        acc.z += (float)h0.z * m0; acc.w += (float)h0.w * m0;
        acc.x += (float)h1.x * m1; acc.y += (float)h1.y * m1;
        acc.z += (float)h1.z * m1; acc.w += (float)h1.w * m1;
        acc.x += (float)h2.x * m2; acc.y += (float)h2.y * m2;
        acc.z += (float)h2.z * m2; acc.w += (float)h2.w * m2;
        acc.x += (float)h3.x * m3; acc.y += (float)h3.y * m3;
        acc.z += (float)h3.z * m3; acc.w += (float)h3.w * m3;
    }
    for (; i < cnt; ++i) {
        unsigned int r = bkt[i];
        half4 h = *reinterpret_cast<const half4*>(emb + (size_t)(r & 0x7FFFFFFFu) * D + col);
        float m = (r >> 31) ? 2.0f : 1.0f;
        acc.x += (float)h.x * m; acc.y += (float)h.y * m;
        acc.z += (float)h.z * m; acc.w += (float)h.w * m;
    }

    // Overflow guard (expected empty)
    int no = *ovf_cnt;
    if (no > 0) {
        if (no > OVF_CAP) no = OVF_CAP;
        for (int k = 0; k < no; ++k) {
            if (ovf[2 * k] == node) {
                unsigned int r = (unsigned int)ovf[2 * k + 1];
                half4 h = *reinterpret_cast<const half4*>(emb + (size_t)(r & 0x7FFFFFFFu) * D + col);
                float m = (r >> 31) ? 2.0f : 1.0f;
                acc.x += (float)h.x * m; acc.y += (float)h.y * m;
                acc.z += (float)h.z * m; acc.w += (float)h.w * m;
            }
        }
    }

    *reinterpret_cast<float4*>(out + (size_t)node * D + col) = acc;
}

// ---------------------------------------------------------------------------
// Fallback (tiny workspace): atomic scatter.
// ---------------------------------------------------------------------------
__global__ void edge_scatter_fallback(const float* __restrict__ ge,
                                      const float* __restrict__ weight,
                                      const int* __restrict__ e_feat,
                                      const int* __restrict__ src,
                                      const int* __restrict__ dst,
                                      float* __restrict__ out, int n_edges) {
    long long tid = (long long)blockIdx.x * blockDim.x + threadIdx.x;
    int edge = (int)(tid >> 5);
    if (edge >= n_edges) return;
    int col = (int)(tid & 31) * 4;
    int e = e_feat[edge];
    float mult = (e == 0 || e == 6 || e == 14 || e == 30) ? 2.0f : 1.0f;
    float4 w = *reinterpret_cast<const float4*>(weight + col);
    float4 g = *reinterpret_cast<const float4*>(ge + (long long)src[edge] * D + col);
    float4 v = elu_mul(g, w);
    float* o = out + (long long)dst[edge] * D + col;
    atomicAdd(o + 0, v.x * mult);
    atomicAdd(o + 1, v.y * mult);
    atomicAdd(o + 2, v.z * mult);
    atomicAdd(o + 3, v.w * mult);
}

extern "C" void kernel_launch(void* const* d_in, const int* in_sizes, int n_in,
                              void* d_out, int out_size, void* d_ws, size_t ws_size,
                              hipStream_t stream) {
    const float* ge     = (const float*)d_in[0];   // [N, 128]
    const float* weight = (const float*)d_in[1];   // [1, 128]
    const int*   e_feat = (const int*)d_in[2];     // [E]
    const int*   src    = (const int*)d_in[3];     // [E]
    const int*   dst    = (const int*)d_in[4];     // [E]
    float* out = (float*)d_out;                    // [N, 128]

    int n_edges = in_sizes[2];
    int n_nodes = out_size / D;

    // Workspace: emb | counts (padded, 64 B/node) | ovf_cnt | bucket | ovf
    auto align256 = [](size_t x) { return (x + 255) & ~(size_t)255; };
    size_t o_emb    = 0;
    size_t o_counts = o_emb    + align256((size_t)n_nodes * D * sizeof(_Float16));
    size_t o_ovfcnt = o_counts + align256((size_t)n_nodes * 64);
    size_t o_bucket = o_ovfcnt + 256;
    size_t o_ovf    = o_bucket + align256((size_t)n_nodes * CAP * 4);
    size_t need     = o_ovf + (size_t)OVF_CAP * 8 + 256;

    // Require <=2 edges per thread for the issue-early pattern.
    const int GRID = 2048;
    bool fits = ((long long)n_edges <= 2LL * GRID * NT);

    if (ws_size < need || !fits) {
        hipMemsetAsync(d_out, 0, (size_t)out_size * sizeof(float), stream);
        long long total = (long long)n_edges * 32;
        edge_scatter_fallback<<<(int)((total + 255) / 256), 256, 0, stream>>>(
            ge, weight, e_feat, src, dst, out, n_edges);
        return;
    }

    char* ws = (char*)d_ws;
    _Float16*     emb     = (_Float16*)(ws + o_emb);
    int*          counts  = (int*)(ws + o_counts);
    int*          ovf_cnt = (int*)(ws + o_ovfcnt);
    unsigned int* bucket  = (unsigned int*)(ws + o_bucket);
    int*          ovf     = (int*)(ws + o_ovf);

    // One memset covers padded counts + ovf_cnt (contiguous).
    hipMemsetAsync(counts, 0, (o_bucket - o_counts), stream);

    fused_pre_kernel<<<GRID, NT, 0, stream>>>(ge, weight, e_feat, src, dst,
                                              emb, counts, bucket, ovf_cnt, ovf,
                                              n_nodes, n_edges);

    long long total = (long long)n_nodes * 32;
    gather_kernel<<<(int)((total + 255) / 256), NT, 0, stream>>>(
        emb, counts, bucket, ovf_cnt, ovf, out, n_nodes);
}